// Round 8
// baseline (312.709 us; speedup 1.0000x reference)
//
#include <hip/hip_runtime.h>
#include <hip/hip_bf16.h>

#define DIM 128
#define PCH 4096   // edges per partition block (LDS-staged)
#define NPB 2048   // nodes per bucket (shift=11)

typedef __attribute__((ext_vector_type(8))) short bf16x8;
typedef __attribute__((ext_vector_type(4))) float f32x4;

__device__ __forceinline__ float bfu_lo(unsigned u) { return __uint_as_float(u << 16); }
__device__ __forceinline__ float bfu_hi(unsigned u) { return __uint_as_float(u & 0xffff0000u); }
__device__ __forceinline__ unsigned short f2bf(float f) {
    unsigned u = __float_as_uint(f);
    u += 0x7fffu + ((u >> 16) & 1u);   // round-to-nearest-even
    return (unsigned short)(u >> 16);
}

__device__ __forceinline__ int edge_at(const void* ei, int idx64, long long pos) {
    return idx64 ? (int)__builtin_nontemporal_load((const long long*)ei + pos)
                 : __builtin_nontemporal_load((const int*)ei + pos);
}

// Block-local edge-width sniff: returns 1 iff edge_index is int64 (odd 32-bit
// words -- high halves -- of the first min(E,4096) entries are all zero).
__device__ __forceinline__ int detect_idx64(const void* ei, int E, unsigned* s_or, int* s_flag) {
    const unsigned* ei_w = (const unsigned*)ei;
    int t = threadIdx.x;
    unsigned o = 0;
    int lim = (E < 4096) ? E : 4096;
    for (int k = t; k < lim; k += 256) o |= ei_w[2 * k + 1];
    s_or[t] = o;
    __syncthreads();
    for (int s = 128; s > 0; s >>= 1) {
        if (t < s) s_or[t] |= s_or[t + s];
        __syncthreads();
    }
    if (t == 0) *s_flag = (s_or[0] == 0u) ? 1 : 0;
    __syncthreads();
    return *s_flag;
}

// Bucket histogram of destinations (+fused width detect). Per-edge increments
// hit LDS; global atomics are only the per-block flush. bcnt pre-zeroed.
__global__ __launch_bounds__(256) void hist_detect(const void* ei, unsigned* bcnt,
                                                   int E, int shift) {
    __shared__ unsigned s_h[512];
    __shared__ unsigned s_or[256];
    __shared__ int s_flag;
    int t = threadIdx.x;
    for (int i = t; i < 512; i += 256) s_h[i] = 0u;
    int idx64 = detect_idx64(ei, E, s_or, &s_flag);
    long long stride = (long long)gridDim.x * 256;
    for (long long e = (long long)blockIdx.x * 256 + t; e < E; e += stride) {
        int d = edge_at(ei, idx64, (long long)E + e);
        atomicAdd(&s_h[d >> shift], 1u);
    }
    __syncthreads();
    for (int i = t; i < 512; i += 256)
        if (s_h[i]) atomicAdd(&bcnt[i], s_h[i]);
}

// LDS-staged partition of raw edges into COARSE destination buckets
// (shift=11 -> ~49 buckets of 2048 nodes). Coarse buckets make the flush
// runs ~PCH/B = 84 edges = 668B -- full-line coalesced -- vs the previous
// 512-bucket variant whose 84B runs caused cross-XCD partial-line churn.
// Flush position is computed directly from the staged d (no binary search).
__global__ __launch_bounds__(256) void partition(const void* ei, const unsigned* __restrict__ bcnt,
                                                 unsigned* bcur0, long long* pout,
                                                 int E, int B, int shift) {
    __shared__ unsigned s_hist[512], s_off[512], s_gbase[512], s_pref[512], s_bbase[512];
    __shared__ unsigned wsum[4];
    __shared__ unsigned s_or[256];
    __shared__ int s_flag;
    __shared__ long long s_p[PCH];
    int t = threadIdx.x;
    long long base = (long long)blockIdx.x * PCH;
    for (int i = t; i < 512; i += 256) { s_hist[i] = 0u; s_off[i] = 0u; }
    int idx64 = detect_idx64(ei, E, s_or, &s_flag);

    // local exclusive scan of global bucket counts -> s_bbase
    {
        unsigned v0 = bcnt[2 * t], v1 = bcnt[2 * t + 1];
        unsigned ps = v0 + v1;
        unsigned s = ps;
        int lane = t & 63;
#pragma unroll
        for (int off = 1; off < 64; off <<= 1) {
            unsigned u = __shfl_up(s, off, 64);
            if (lane >= off) s += u;
        }
        int w = t >> 6;
        if (lane == 63) wsum[w] = s;
        __syncthreads();
        unsigned woff = 0;
        for (int j = 0; j < w; j++) woff += wsum[j];
        unsigned excl = woff + s - ps;
        s_bbase[2 * t] = excl;
        s_bbase[2 * t + 1] = excl + v0;
    }
    __syncthreads();

    // load own edges into registers, LDS histogram
    int d_[PCH / 256], s_[PCH / 256];
#pragma unroll 4
    for (int j = 0; j < PCH / 256; j++) {
        long long e = base + j * 256 + t;
        if (e < E) {
            d_[j] = edge_at(ei, idx64, (long long)E + e);
            s_[j] = edge_at(ei, idx64, e);
            atomicAdd(&s_hist[d_[j] >> shift], 1u);
        } else d_[j] = -1;
    }
    __syncthreads();

    // exclusive scan of local 512 counts -> s_pref
    {
        unsigned v0 = s_hist[2 * t], v1 = s_hist[2 * t + 1];
        unsigned ps = v0 + v1;
        unsigned s = ps;
        int lane = t & 63;
#pragma unroll
        for (int off = 1; off < 64; off <<= 1) {
            unsigned u = __shfl_up(s, off, 64);
            if (lane >= off) s += u;
        }
        int w = t >> 6;
        if (lane == 63) wsum[w] = s;
        __syncthreads();
        unsigned woff = 0;
        for (int j = 0; j < w; j++) woff += wsum[j];
        unsigned excl = woff + s - ps;
        s_pref[2 * t] = excl;
        s_pref[2 * t + 1] = excl + v0;
    }
    __syncthreads();

    for (int i = t; i < B; i += 256)
        if (s_hist[i]) s_gbase[i] = s_bbase[i] + atomicAdd(&bcur0[i], s_hist[i]);
#pragma unroll 4
    for (int j = 0; j < PCH / 256; j++)
        if (d_[j] >= 0) {
            int b = d_[j] >> shift;
            unsigned p = s_pref[b] + atomicAdd(&s_off[b], 1u);
            s_p[p] = ((long long)s_[j] << 32) | (unsigned)d_[j];
        }
    __syncthreads();
    long long rem = (long long)E - base;
    unsigned tot = (rem < PCH) ? (unsigned)rem : (unsigned)PCH;
    for (unsigned i = t; i < tot; i += 256) {
        long long v = s_p[i];
        int b = ((int)v) >> shift;              // direct bucket recompute
        pout[s_gbase[b] + (i - s_pref[b])] = v;
    }
}

// One block per bucket (<=2048 nodes). Recomputes bucket bases locally from
// bcnt. Degree histogram, 2048-wide prefix scan (8 elems/thread), dis, and
// CSR fill all via LDS counters -- zero global scattered atomics.
__global__ __launch_bounds__(256) void build_csr(const long long* __restrict__ pairs,
                                                 const unsigned* __restrict__ bcnt,
                                                 unsigned* deg, unsigned* row_start,
                                                 float* dis, int* col_src,
                                                 int N, int shift) {
    __shared__ unsigned cnt[NPB], cur[NPB], pref[NPB];
    __shared__ unsigned s_bb[513];
    __shared__ unsigned wsum[4];
    int b = blockIdx.x, t = threadIdx.x;
    int nodeLo = b << shift;

    // local exclusive scan of global bucket counts -> bucket [lo,hi)
    {
        unsigned v0 = bcnt[2 * t], v1 = bcnt[2 * t + 1];
        unsigned ps = v0 + v1;
        unsigned s = ps;
        int lane = t & 63;
#pragma unroll
        for (int off = 1; off < 64; off <<= 1) {
            unsigned u = __shfl_up(s, off, 64);
            if (lane >= off) s += u;
        }
        int w = t >> 6;
        if (lane == 63) wsum[w] = s;
        __syncthreads();
        unsigned woff = 0;
        for (int j = 0; j < w; j++) woff += wsum[j];
        unsigned excl = woff + s - ps;
        s_bb[2 * t] = excl;
        s_bb[2 * t + 1] = excl + v0;
        if (t == 255) s_bb[512] = excl + ps;
    }
    __syncthreads();
    unsigned lo = s_bb[b], hi = s_bb[b + 1];

#pragma unroll
    for (int j = 0; j < NPB / 256; j++) cnt[t + j * 256] = 0u;
    __syncthreads();
    for (unsigned e = lo + t; e < hi; e += 256) {
        int d = (int)pairs[e];
        atomicAdd(&cnt[d - nodeLo], 1u);
    }
    __syncthreads();

    // exclusive scan of NPB counts, 8 per thread (contiguous chunk)
    {
        unsigned loc[8];
        unsigned run = 0;
#pragma unroll
        for (int j = 0; j < 8; j++) { loc[j] = run; run += cnt[t * 8 + j]; }
        unsigned s = run;
        int lane = t & 63;
#pragma unroll
        for (int off = 1; off < 64; off <<= 1) {
            unsigned u = __shfl_up(s, off, 64);
            if (lane >= off) s += u;
        }
        int w = t >> 6;
        if (lane == 63) wsum[w] = s;
        __syncthreads();
        unsigned woff = 0;
        for (int j = 0; j < w; j++) woff += wsum[j];
        unsigned tbase = woff + s - run;        // exclusive thread base
#pragma unroll
        for (int j = 0; j < 8; j++) pref[t * 8 + j] = tbase + loc[j];
    }
    __syncthreads();

#pragma unroll
    for (int j = 0; j < NPB / 256; j++) {
        int i = t + j * 256;
        int node = nodeLo + i;
        unsigned rs = lo + pref[i];
        if (node < N) {
            unsigned c = cnt[i];
            deg[node] = c;
            row_start[node] = rs;
            dis[node] = rsqrtf((float)c + 1.0f);   // +1 self-loop
        }
        cur[i] = rs;
    }
    __syncthreads();
    for (unsigned e = lo + t; e < hi; e += 256) {
        long long v = pairs[e];
        int d = (int)v;
        int sv = (int)(v >> 32);
        unsigned pos = atomicAdd(&cur[d - nodeLo], 1u);
        col_src[pos] = sv;
    }
}

// xps = dis[row] * (x @ W), bf16 MFMA, fp32 x in / packed-bf16 out (pre-scaled).
// W transpose+bf16-convert fused into LDS (padded stride 136 shorts).
// Operand swap: mfma(Wfrag, Xfrag, acc) -> lane holds out[row=rowBase+l15][col=quad*4+reg]
__global__ __launch_bounds__(256) void gemm_xw(const float* __restrict__ x,
                                               const float* __restrict__ W,
                                               const float* __restrict__ dis,
                                               unsigned short* __restrict__ xps, int N) {
    __shared__ unsigned short wt[128 * 136];
    int tid = threadIdx.x;
    for (int idx = tid; idx < DIM * DIM; idx += 256) {
        int k = idx >> 7, n = idx & 127;        // idx = k*128+n -> coalesced W read
        wt[n * 136 + k] = f2bf(W[idx]);
    }
    __syncthreads();

    int wv = tid >> 6, lane = tid & 63;
    int l15 = lane & 15, quad = lane >> 4;
    int rowBase = blockIdx.x * 128 + wv * 32;

    f32x4 acc[2][8];
#pragma unroll
    for (int mt = 0; mt < 2; mt++)
#pragma unroll
        for (int nt = 0; nt < 8; nt++)
            acc[mt][nt] = (f32x4){0.f, 0.f, 0.f, 0.f};

#pragma unroll
    for (int k0 = 0; k0 < DIM; k0 += 32) {
        bf16x8 aa[2], bb[8];
#pragma unroll
        for (int mt = 0; mt < 2; mt++) {
            int r = rowBase + mt * 16 + l15;
            if (r > N - 1) r = N - 1;           // clamp; garbage rows never stored
            const float* xf = x + (size_t)r * DIM + k0 + quad * 8;
            float4 u0 = ((const float4*)xf)[0];
            float4 u1 = ((const float4*)xf)[1];
            bf16x8 a;
            a[0] = (short)f2bf(u0.x); a[1] = (short)f2bf(u0.y);
            a[2] = (short)f2bf(u0.z); a[3] = (short)f2bf(u0.w);
            a[4] = (short)f2bf(u1.x); a[5] = (short)f2bf(u1.y);
            a[6] = (short)f2bf(u1.z); a[7] = (short)f2bf(u1.w);
            aa[mt] = a;
        }
#pragma unroll
        for (int nt = 0; nt < 8; nt++)
            bb[nt] = *(const bf16x8*)(wt + (nt * 16 + l15) * 136 + k0 + quad * 8);
#pragma unroll
        for (int mt = 0; mt < 2; mt++)
#pragma unroll
            for (int nt = 0; nt < 8; nt++)
                acc[mt][nt] = __builtin_amdgcn_mfma_f32_16x16x32_bf16(bb[nt], aa[mt], acc[mt][nt], 0, 0, 0);
    }

#pragma unroll
    for (int mt = 0; mt < 2; mt++) {
        int r = rowBase + mt * 16 + l15;
        if (r < N) {
            float sc = dis[r];                  // pre-scale by source-side dis
#pragma unroll
            for (int nt = 0; nt < 8; nt++) {
                int c0 = nt * 16 + quad * 4;
                ushort4 o;
                o.x = f2bf(acc[mt][nt][0] * sc);
                o.y = f2bf(acc[mt][nt][1] * sc);
                o.z = f2bf(acc[mt][nt][2] * sc);
                o.w = f2bf(acc[mt][nt][3] * sc);
                *(ushort4*)(xps + (size_t)r * DIM + c0) = o;
            }
        }
    }
}

// One wave per node. 16 lanes per edge row (uint4 = 16B = 8 bf16 each).
// R5 structure + depth-2 register prefetch (a/b double buffer): doubles
// in-flight gathers per wave (2->4) while staying in the <=64-VGPR /
// 8-waves-per-SIMD tier. (R7 lesson: the 16-deep batch pushed VGPR to 68,
// halved occupancy, and REGRESSED -- TLP was what hid the latency.)
// Self-loop is virtual slot `cnt` (index wid). out[d] = dis[d] * sum(xps).
__global__ __launch_bounds__(256) void aggregate(const unsigned short* __restrict__ xps,
                                                 const unsigned* __restrict__ row_start,
                                                 const unsigned* __restrict__ deg,
                                                 const float* __restrict__ dis,
                                                 const int* __restrict__ col_src,
                                                 float* __restrict__ out, int N) {
    int wid = (int)((blockIdx.x * 256 + threadIdx.x) >> 6);
    if (wid >= N) return;
    int lane = threadIdx.x & 63;
    int grp = lane >> 4, lin = lane & 15;
    const uint4* xp4 = (const uint4*)xps;       // row = 16 x uint4

    float acc[8];
#pragma unroll
    for (int j = 0; j < 8; j++) acc[j] = 0.f;

    unsigned rs = row_start[wid];
    unsigned cnt = deg[wid];
    unsigned tot = cnt + 1;                      // + virtual self slot

    for (unsigned base = 0; base < tot; base += 64) {
        unsigned slot = base + (unsigned)lane;
        int idx = (slot < cnt) ? col_src[rs + slot] : wid;   // invalid/self -> wid (safe)
        unsigned rem = tot - base; if (rem > 64) rem = 64;
        unsigned kmax = (rem + 7) >> 3;          // wave-uniform: 1..8 q-steps

        // preload q=0 into (a0,a1)
        int p0 = __shfl(idx, grp, 64);
        int p1 = __shfl(idx, grp + 4, 64);
        float ma0 = ((unsigned)grp < rem) ? 1.f : 0.f;
        float ma1 = ((unsigned)(grp + 4) < rem) ? 1.f : 0.f;
        uint4 a0 = xp4[(size_t)p0 * 16 + lin];
        uint4 a1 = xp4[(size_t)p1 * 16 + lin];

#pragma unroll
        for (int q = 0; q < 8; q++) {
            if ((unsigned)q < kmax) {
                uint4 b0, b1;
                float mb0 = 0.f, mb1 = 0.f;
                bool pf = ((unsigned)(q + 1) < kmax);
                if (pf) {                        // issue next pair before consuming
                    unsigned sl0 = (unsigned)(q + 1) * 8 + (unsigned)grp;
                    unsigned sl1 = sl0 + 4;
                    int t0 = __shfl(idx, (int)sl0, 64);
                    int t1 = __shfl(idx, (int)sl1, 64);
                    mb0 = (sl0 < rem) ? 1.f : 0.f;
                    mb1 = (sl1 < rem) ? 1.f : 0.f;
                    b0 = xp4[(size_t)t0 * 16 + lin];
                    b1 = xp4[(size_t)t1 * 16 + lin];
                }
                acc[0] = fmaf(bfu_lo(a0.x), ma0, acc[0]);
                acc[1] = fmaf(bfu_hi(a0.x), ma0, acc[1]);
                acc[2] = fmaf(bfu_lo(a0.y), ma0, acc[2]);
                acc[3] = fmaf(bfu_hi(a0.y), ma0, acc[3]);
                acc[4] = fmaf(bfu_lo(a0.z), ma0, acc[4]);
                acc[5] = fmaf(bfu_hi(a0.z), ma0, acc[5]);
                acc[6] = fmaf(bfu_lo(a0.w), ma0, acc[6]);
                acc[7] = fmaf(bfu_hi(a0.w), ma0, acc[7]);
                acc[0] = fmaf(bfu_lo(a1.x), ma1, acc[0]);
                acc[1] = fmaf(bfu_hi(a1.x), ma1, acc[1]);
                acc[2] = fmaf(bfu_lo(a1.y), ma1, acc[2]);
                acc[3] = fmaf(bfu_hi(a1.y), ma1, acc[3]);
                acc[4] = fmaf(bfu_lo(a1.z), ma1, acc[4]);
                acc[5] = fmaf(bfu_hi(a1.z), ma1, acc[5]);
                acc[6] = fmaf(bfu_lo(a1.w), ma1, acc[6]);
                acc[7] = fmaf(bfu_hi(a1.w), ma1, acc[7]);
                if (pf) { a0 = b0; a1 = b1; ma0 = mb0; ma1 = mb1; }
            }
        }
    }

    // reduce across the 4 groups (lanes differing in bits 4 and 5)
#pragma unroll
    for (int j = 0; j < 8; j++) {
        acc[j] += __shfl_xor(acc[j], 16, 64);
        acc[j] += __shfl_xor(acc[j], 32, 64);
    }

    float di = dis[wid];
    if (grp < 2) {                               // 32 lanes store the 512B row
        int jb = (grp & 1) * 4;
        float4 o;
        o.x = acc[jb + 0] * di;
        o.y = acc[jb + 1] * di;
        o.z = acc[jb + 2] * di;
        o.w = acc[jb + 3] * di;
        *(float4*)(out + (size_t)wid * DIM + lin * 8 + jb) = o;
    }
}

extern "C" void kernel_launch(void* const* d_in, const int* in_sizes, int n_in,
                              void* d_out, int out_size, void* d_ws, size_t ws_size,
                              hipStream_t stream) {
    const int N = in_sizes[0] / DIM;
    const int E = in_sizes[1] / 2;
    const float* x = (const float*)d_in[0];                     // fp32 [N][128]
    const void* ei = d_in[1];                                   // int32 or int64 [2][E]
    const float* W = (const float*)d_in[2];                     // fp32 [128][128]
    float* out = (float*)d_out;                                 // fp32 [N][128]

    // bucket geometry: 2048 nodes per bucket (shift=11), B <= 512 buckets.
    // Valid for N <= 1M (this problem: N=100000 -> B=49).
    int shift = 11;
    while ((((long long)N + (1LL << shift) - 1) >> shift) > 512) shift++;
    int B = (int)(((long long)N + (1LL << shift) - 1) >> shift);

    char* wsp = (char*)d_ws;
    size_t off = 0;
    auto alloc = [&](size_t b) { void* p = wsp + off; off += (b + 255) & ~(size_t)255; return p; };
    unsigned* bcnt       = (unsigned*)alloc(4096);              // [0..511]=bcnt, [512..1023]=bcur0
    unsigned* bcur0      = bcnt + 512;
    unsigned* deg        = (unsigned*)alloc((size_t)N * 4);
    unsigned* row_start  = (unsigned*)alloc((size_t)N * 4);
    float*    dis        = (float*)alloc((size_t)N * 4);
    int*      col_src    = (int*)alloc((size_t)E * 4);
    unsigned short* xps  = (unsigned short*)alloc((size_t)N * DIM * 2);

    // pairs alias the xps region (E*8 = 12.8MB <= N*DIM*2 = 25.6MB): dead
    // before gemm_xw writes xps (stream-ordered), so no extra workspace.
    long long* pairs = (long long*)xps;
    if ((size_t)E * 8 > (size_t)N * DIM * 2 && off + (size_t)E * 8 <= ws_size)
        pairs = (long long*)alloc((size_t)E * 8);

    hipMemsetAsync(bcnt, 0, 4096, stream);
    hist_detect<<<512, 256, 0, stream>>>(ei, bcnt, E, shift);
    partition<<<(E + PCH - 1) / PCH, 256, 0, stream>>>(ei, bcnt, bcur0, pairs, E, B, shift);
    build_csr<<<B, 256, 0, stream>>>(pairs, bcnt, deg, row_start, dis, col_src, N, shift);
    gemm_xw<<<(N + 127) / 128, 256, 0, stream>>>(x, W, dis, xps, N);
    aggregate<<<(N + 3) / 4, 256, 0, stream>>>(xps, row_start, deg, dis, col_src, out, N);
}

// Round 9
// 251.354 us; speedup vs baseline: 1.2441x; 1.2441x over previous
//
#include <hip/hip_runtime.h>
#include <hip/hip_bf16.h>

#define DIM 128
#define PCH 4096   // edges per partition block (LDS-staged)

typedef __attribute__((ext_vector_type(8))) short bf16x8;
typedef __attribute__((ext_vector_type(4))) float f32x4;

__device__ __forceinline__ float bfu_lo(unsigned u) { return __uint_as_float(u << 16); }
__device__ __forceinline__ float bfu_hi(unsigned u) { return __uint_as_float(u & 0xffff0000u); }
__device__ __forceinline__ unsigned short f2bf(float f) {
    unsigned u = __float_as_uint(f);
    u += 0x7fffu + ((u >> 16) & 1u);   // round-to-nearest-even
    return (unsigned short)(u >> 16);
}

__device__ __forceinline__ int edge_at(const void* ei, int idx64, long long pos) {
    return idx64 ? (int)__builtin_nontemporal_load((const long long*)ei + pos)
                 : __builtin_nontemporal_load((const int*)ei + pos);
}

// Block-local edge-width sniff: returns 1 iff edge_index is int64 (odd 32-bit
// words -- high halves -- of the first min(E,4096) entries are all zero).
__device__ __forceinline__ int detect_idx64(const void* ei, int E, unsigned* s_or, int* s_flag) {
    const unsigned* ei_w = (const unsigned*)ei;
    int t = threadIdx.x;
    unsigned o = 0;
    int lim = (E < 4096) ? E : 4096;
    for (int k = t; k < lim; k += 256) o |= ei_w[2 * k + 1];
    s_or[t] = o;
    __syncthreads();
    for (int s = 128; s > 0; s >>= 1) {
        if (t < s) s_or[t] |= s_or[t + s];
        __syncthreads();
    }
    if (t == 0) *s_flag = (s_or[0] == 0u) ? 1 : 0;
    __syncthreads();
    return *s_flag;
}

// Bucket histogram of destinations (+fused width detect). Per-edge increments
// hit LDS; global atomics are only the per-block flush. bcnt pre-zeroed.
__global__ __launch_bounds__(256) void hist_detect(const void* ei, unsigned* bcnt,
                                                   int E, int shift) {
    __shared__ unsigned s_h[512];
    __shared__ unsigned s_or[256];
    __shared__ int s_flag;
    int t = threadIdx.x;
    for (int i = t; i < 512; i += 256) s_h[i] = 0u;
    int idx64 = detect_idx64(ei, E, s_or, &s_flag);
    long long stride = (long long)gridDim.x * 256;
    for (long long e = (long long)blockIdx.x * 256 + t; e < E; e += stride) {
        int d = edge_at(ei, idx64, (long long)E + e);
        atomicAdd(&s_h[d >> shift], 1u);
    }
    __syncthreads();
    for (int i = t; i < 512; i += 256)
        if (s_h[i]) atomicAdd(&bcnt[i], s_h[i]);
}

// LDS-staged partition of raw edges into destination buckets (shift=8,
// B<=512 buckets of 256 nodes -- R8 lesson: coarse buckets starve the build
// pass's grid; fine buckets keep B ~ 1.5x CUs). Flush position is computed
// directly from the staged d (R8's improvement -- no binary search).
__global__ __launch_bounds__(256) void partition(const void* ei, const unsigned* __restrict__ bcnt,
                                                 unsigned* bcur0, long long* pout,
                                                 int E, int B, int shift) {
    __shared__ unsigned s_hist[512], s_off[512], s_gbase[512], s_pref[512], s_bbase[512];
    __shared__ unsigned wsum[4];
    __shared__ unsigned s_or[256];
    __shared__ int s_flag;
    __shared__ long long s_p[PCH];
    int t = threadIdx.x;
    long long base = (long long)blockIdx.x * PCH;
    for (int i = t; i < 512; i += 256) { s_hist[i] = 0u; s_off[i] = 0u; }
    int idx64 = detect_idx64(ei, E, s_or, &s_flag);

    // local exclusive scan of global bucket counts -> s_bbase
    {
        unsigned v0 = bcnt[2 * t], v1 = bcnt[2 * t + 1];
        unsigned ps = v0 + v1;
        unsigned s = ps;
        int lane = t & 63;
#pragma unroll
        for (int off = 1; off < 64; off <<= 1) {
            unsigned u = __shfl_up(s, off, 64);
            if (lane >= off) s += u;
        }
        int w = t >> 6;
        if (lane == 63) wsum[w] = s;
        __syncthreads();
        unsigned woff = 0;
        for (int j = 0; j < w; j++) woff += wsum[j];
        unsigned excl = woff + s - ps;
        s_bbase[2 * t] = excl;
        s_bbase[2 * t + 1] = excl + v0;
    }
    __syncthreads();

    // load own edges into registers, LDS histogram
    int d_[PCH / 256], s_[PCH / 256];
#pragma unroll 4
    for (int j = 0; j < PCH / 256; j++) {
        long long e = base + j * 256 + t;
        if (e < E) {
            d_[j] = edge_at(ei, idx64, (long long)E + e);
            s_[j] = edge_at(ei, idx64, e);
            atomicAdd(&s_hist[d_[j] >> shift], 1u);
        } else d_[j] = -1;
    }
    __syncthreads();

    // exclusive scan of local 512 counts -> s_pref
    {
        unsigned v0 = s_hist[2 * t], v1 = s_hist[2 * t + 1];
        unsigned ps = v0 + v1;
        unsigned s = ps;
        int lane = t & 63;
#pragma unroll
        for (int off = 1; off < 64; off <<= 1) {
            unsigned u = __shfl_up(s, off, 64);
            if (lane >= off) s += u;
        }
        int w = t >> 6;
        if (lane == 63) wsum[w] = s;
        __syncthreads();
        unsigned woff = 0;
        for (int j = 0; j < w; j++) woff += wsum[j];
        unsigned excl = woff + s - ps;
        s_pref[2 * t] = excl;
        s_pref[2 * t + 1] = excl + v0;
    }
    __syncthreads();

    for (int i = t; i < B; i += 256)
        if (s_hist[i]) s_gbase[i] = s_bbase[i] + atomicAdd(&bcur0[i], s_hist[i]);
#pragma unroll 4
    for (int j = 0; j < PCH / 256; j++)
        if (d_[j] >= 0) {
            int b = d_[j] >> shift;
            unsigned p = s_pref[b] + atomicAdd(&s_off[b], 1u);
            s_p[p] = ((long long)s_[j] << 32) | (unsigned)d_[j];
        }
    __syncthreads();
    long long rem = (long long)E - base;
    unsigned tot = (rem < PCH) ? (unsigned)rem : (unsigned)PCH;
    for (unsigned i = t; i < tot; i += 256) {
        long long v = s_p[i];
        int b = ((int)v) >> shift;              // direct bucket recompute (no search)
        pout[s_gbase[b] + (i - s_pref[b])] = v;
    }
}

// One block per bucket (256 nodes). Recomputes bucket bases locally from
// bcnt. Degree histogram, prefix scan, dis, and CSR fill all via LDS
// counters -- zero global scattered atomics.
__global__ __launch_bounds__(256) void build_csr(const long long* __restrict__ pairs,
                                                 const unsigned* __restrict__ bcnt,
                                                 unsigned* deg, unsigned* row_start,
                                                 float* dis, int* col_src,
                                                 int N, int shift) {
    __shared__ unsigned cnt[512], cur[512], pref[512];
    __shared__ unsigned s_bb[513];
    __shared__ unsigned wsum[4];
    int b = blockIdx.x, t = threadIdx.x;
    int npb = 1 << shift;
    if (npb > 512) npb = 512;                   // defensive; caller guarantees <=512
    int nodeLo = b << shift;

    // local exclusive scan of global bucket counts -> bucket [lo,hi)
    {
        unsigned v0 = bcnt[2 * t], v1 = bcnt[2 * t + 1];
        unsigned ps = v0 + v1;
        unsigned s = ps;
        int lane = t & 63;
#pragma unroll
        for (int off = 1; off < 64; off <<= 1) {
            unsigned u = __shfl_up(s, off, 64);
            if (lane >= off) s += u;
        }
        int w = t >> 6;
        if (lane == 63) wsum[w] = s;
        __syncthreads();
        unsigned woff = 0;
        for (int j = 0; j < w; j++) woff += wsum[j];
        unsigned excl = woff + s - ps;
        s_bb[2 * t] = excl;
        s_bb[2 * t + 1] = excl + v0;
        if (t == 255) s_bb[512] = excl + ps;
    }
    __syncthreads();
    unsigned lo = s_bb[b], hi = s_bb[b + 1];

    for (int i = t; i < npb; i += 256) cnt[i] = 0u;
    __syncthreads();
    for (unsigned e = lo + t; e < hi; e += 256) {
        int d = (int)pairs[e];
        atomicAdd(&cnt[d - nodeLo], 1u);
    }
    __syncthreads();
    // exclusive scan of npb (<=512) counts, 2 per thread
    unsigned v0 = (2 * t < npb) ? cnt[2 * t] : 0u;
    unsigned v1 = (2 * t + 1 < npb) ? cnt[2 * t + 1] : 0u;
    unsigned ps = v0 + v1;
    unsigned s = ps;
    int lane = t & 63;
#pragma unroll
    for (int off = 1; off < 64; off <<= 1) {
        unsigned u = __shfl_up(s, off, 64);
        if (lane >= off) s += u;
    }
    int w = t >> 6;
    if (lane == 63) wsum[w] = s;
    __syncthreads();
    unsigned woff = 0;
    for (int j = 0; j < w; j++) woff += wsum[j];
    unsigned excl = woff + s - ps;
    if (2 * t < npb) pref[2 * t] = excl;
    if (2 * t + 1 < npb) pref[2 * t + 1] = excl + v0;
    __syncthreads();
    for (int i = t; i < npb; i += 256) {
        int node = nodeLo + i;
        unsigned rs = lo + pref[i];
        if (node < N) {
            unsigned c = cnt[i];
            deg[node] = c;
            row_start[node] = rs;
            dis[node] = rsqrtf((float)c + 1.0f);   // +1 self-loop
        }
        cur[i] = rs;
    }
    __syncthreads();
    for (unsigned e = lo + t; e < hi; e += 256) {
        long long v = pairs[e];
        int d = (int)v;
        int sv = (int)(v >> 32);
        unsigned pos = atomicAdd(&cur[d - nodeLo], 1u);
        col_src[pos] = sv;
    }
}

// xps = dis[row] * (x @ W), bf16 MFMA, fp32 x in / packed-bf16 out (pre-scaled).
// W transpose+bf16-convert fused into LDS (padded stride 136 shorts).
// Operand swap: mfma(Wfrag, Xfrag, acc) -> lane holds out[row=rowBase+l15][col=quad*4+reg]
__global__ __launch_bounds__(256) void gemm_xw(const float* __restrict__ x,
                                               const float* __restrict__ W,
                                               const float* __restrict__ dis,
                                               unsigned short* __restrict__ xps, int N) {
    __shared__ unsigned short wt[128 * 136];
    int tid = threadIdx.x;
    for (int idx = tid; idx < DIM * DIM; idx += 256) {
        int k = idx >> 7, n = idx & 127;        // idx = k*128+n -> coalesced W read
        wt[n * 136 + k] = f2bf(W[idx]);
    }
    __syncthreads();

    int wv = tid >> 6, lane = tid & 63;
    int l15 = lane & 15, quad = lane >> 4;
    int rowBase = blockIdx.x * 128 + wv * 32;

    f32x4 acc[2][8];
#pragma unroll
    for (int mt = 0; mt < 2; mt++)
#pragma unroll
        for (int nt = 0; nt < 8; nt++)
            acc[mt][nt] = (f32x4){0.f, 0.f, 0.f, 0.f};

#pragma unroll
    for (int k0 = 0; k0 < DIM; k0 += 32) {
        bf16x8 aa[2], bb[8];
#pragma unroll
        for (int mt = 0; mt < 2; mt++) {
            int r = rowBase + mt * 16 + l15;
            if (r > N - 1) r = N - 1;           // clamp; garbage rows never stored
            const float* xf = x + (size_t)r * DIM + k0 + quad * 8;
            float4 u0 = ((const float4*)xf)[0];
            float4 u1 = ((const float4*)xf)[1];
            bf16x8 a;
            a[0] = (short)f2bf(u0.x); a[1] = (short)f2bf(u0.y);
            a[2] = (short)f2bf(u0.z); a[3] = (short)f2bf(u0.w);
            a[4] = (short)f2bf(u1.x); a[5] = (short)f2bf(u1.y);
            a[6] = (short)f2bf(u1.z); a[7] = (short)f2bf(u1.w);
            aa[mt] = a;
        }
#pragma unroll
        for (int nt = 0; nt < 8; nt++)
            bb[nt] = *(const bf16x8*)(wt + (nt * 16 + l15) * 136 + k0 + quad * 8);
#pragma unroll
        for (int mt = 0; mt < 2; mt++)
#pragma unroll
            for (int nt = 0; nt < 8; nt++)
                acc[mt][nt] = __builtin_amdgcn_mfma_f32_16x16x32_bf16(bb[nt], aa[mt], acc[mt][nt], 0, 0, 0);
    }

#pragma unroll
    for (int mt = 0; mt < 2; mt++) {
        int r = rowBase + mt * 16 + l15;
        if (r < N) {
            float sc = dis[r];                  // pre-scale by source-side dis
#pragma unroll
            for (int nt = 0; nt < 8; nt++) {
                int c0 = nt * 16 + quad * 4;
                ushort4 o;
                o.x = f2bf(acc[mt][nt][0] * sc);
                o.y = f2bf(acc[mt][nt][1] * sc);
                o.z = f2bf(acc[mt][nt][2] * sc);
                o.w = f2bf(acc[mt][nt][3] * sc);
                *(ushort4*)(xps + (size_t)r * DIM + c0) = o;
            }
        }
    }
}

// One wave per node. 16 lanes per edge row (uint4 = 16B = 8 bf16 each).
// Depth-2 register prefetch (a/b double buffer): doubles in-flight gathers
// per wave (2->4) while staying in the <=64-VGPR / 8-waves-per-SIMD tier.
// (R7 lesson: deeper batching spills past 64 VGPR, halves occupancy, and
// regresses -- TLP is what hides the latency here.)
// Self-loop is virtual slot `cnt` (index wid). out[d] = dis[d] * sum(xps).
__global__ __launch_bounds__(256) void aggregate(const unsigned short* __restrict__ xps,
                                                 const unsigned* __restrict__ row_start,
                                                 const unsigned* __restrict__ deg,
                                                 const float* __restrict__ dis,
                                                 const int* __restrict__ col_src,
                                                 float* __restrict__ out, int N) {
    int wid = (int)((blockIdx.x * 256 + threadIdx.x) >> 6);
    if (wid >= N) return;
    int lane = threadIdx.x & 63;
    int grp = lane >> 4, lin = lane & 15;
    const uint4* xp4 = (const uint4*)xps;       // row = 16 x uint4

    float acc[8];
#pragma unroll
    for (int j = 0; j < 8; j++) acc[j] = 0.f;

    unsigned rs = row_start[wid];
    unsigned cnt = deg[wid];
    unsigned tot = cnt + 1;                      // + virtual self slot

    for (unsigned base = 0; base < tot; base += 64) {
        unsigned slot = base + (unsigned)lane;
        int idx = (slot < cnt) ? col_src[rs + slot] : wid;   // invalid/self -> wid (safe)
        unsigned rem = tot - base; if (rem > 64) rem = 64;
        unsigned kmax = (rem + 7) >> 3;          // wave-uniform: 1..8 q-steps

        // preload q=0 into (a0,a1)
        int p0 = __shfl(idx, grp, 64);
        int p1 = __shfl(idx, grp + 4, 64);
        float ma0 = ((unsigned)grp < rem) ? 1.f : 0.f;
        float ma1 = ((unsigned)(grp + 4) < rem) ? 1.f : 0.f;
        uint4 a0 = xp4[(size_t)p0 * 16 + lin];
        uint4 a1 = xp4[(size_t)p1 * 16 + lin];

#pragma unroll
        for (int q = 0; q < 8; q++) {
            if ((unsigned)q < kmax) {
                uint4 b0, b1;
                float mb0 = 0.f, mb1 = 0.f;
                bool pf = ((unsigned)(q + 1) < kmax);
                if (pf) {                        // issue next pair before consuming
                    unsigned sl0 = (unsigned)(q + 1) * 8 + (unsigned)grp;
                    unsigned sl1 = sl0 + 4;
                    int t0 = __shfl(idx, (int)sl0, 64);
                    int t1 = __shfl(idx, (int)sl1, 64);
                    mb0 = (sl0 < rem) ? 1.f : 0.f;
                    mb1 = (sl1 < rem) ? 1.f : 0.f;
                    b0 = xp4[(size_t)t0 * 16 + lin];
                    b1 = xp4[(size_t)t1 * 16 + lin];
                }
                acc[0] = fmaf(bfu_lo(a0.x), ma0, acc[0]);
                acc[1] = fmaf(bfu_hi(a0.x), ma0, acc[1]);
                acc[2] = fmaf(bfu_lo(a0.y), ma0, acc[2]);
                acc[3] = fmaf(bfu_hi(a0.y), ma0, acc[3]);
                acc[4] = fmaf(bfu_lo(a0.z), ma0, acc[4]);
                acc[5] = fmaf(bfu_hi(a0.z), ma0, acc[5]);
                acc[6] = fmaf(bfu_lo(a0.w), ma0, acc[6]);
                acc[7] = fmaf(bfu_hi(a0.w), ma0, acc[7]);
                acc[0] = fmaf(bfu_lo(a1.x), ma1, acc[0]);
                acc[1] = fmaf(bfu_hi(a1.x), ma1, acc[1]);
                acc[2] = fmaf(bfu_lo(a1.y), ma1, acc[2]);
                acc[3] = fmaf(bfu_hi(a1.y), ma1, acc[3]);
                acc[4] = fmaf(bfu_lo(a1.z), ma1, acc[4]);
                acc[5] = fmaf(bfu_hi(a1.z), ma1, acc[5]);
                acc[6] = fmaf(bfu_lo(a1.w), ma1, acc[6]);
                acc[7] = fmaf(bfu_hi(a1.w), ma1, acc[7]);
                if (pf) { a0 = b0; a1 = b1; ma0 = mb0; ma1 = mb1; }
            }
        }
    }

    // reduce across the 4 groups (lanes differing in bits 4 and 5)
#pragma unroll
    for (int j = 0; j < 8; j++) {
        acc[j] += __shfl_xor(acc[j], 16, 64);
        acc[j] += __shfl_xor(acc[j], 32, 64);
    }

    float di = dis[wid];
    if (grp < 2) {                               // 32 lanes store the 512B row
        int jb = (grp & 1) * 4;
        float4 o;
        o.x = acc[jb + 0] * di;
        o.y = acc[jb + 1] * di;
        o.z = acc[jb + 2] * di;
        o.w = acc[jb + 3] * di;
        *(float4*)(out + (size_t)wid * DIM + lin * 8 + jb) = o;
    }
}

extern "C" void kernel_launch(void* const* d_in, const int* in_sizes, int n_in,
                              void* d_out, int out_size, void* d_ws, size_t ws_size,
                              hipStream_t stream) {
    const int N = in_sizes[0] / DIM;
    const int E = in_sizes[1] / 2;
    const float* x = (const float*)d_in[0];                     // fp32 [N][128]
    const void* ei = d_in[1];                                   // int32 or int64 [2][E]
    const float* W = (const float*)d_in[2];                     // fp32 [128][128]
    float* out = (float*)d_out;                                 // fp32 [N][128]

    // bucket geometry: 256 nodes per bucket (shift=8), B <= 512 buckets.
    // R8 lesson: coarse buckets (shift=11, B=49) starve build_csr's grid
    // (1.9% occupancy, 79us). B ~ 1.5x CU count is the sweet spot.
    int shift = 8;
    while ((((long long)N + (1LL << shift) - 1) >> shift) > 512 && shift < 9) shift++;
    int B = (int)(((long long)N + (1LL << shift) - 1) >> shift);

    char* wsp = (char*)d_ws;
    size_t off = 0;
    auto alloc = [&](size_t b) { void* p = wsp + off; off += (b + 255) & ~(size_t)255; return p; };
    unsigned* bcnt       = (unsigned*)alloc(4096);              // [0..511]=bcnt, [512..1023]=bcur0
    unsigned* bcur0      = bcnt + 512;
    unsigned* deg        = (unsigned*)alloc((size_t)N * 4);
    unsigned* row_start  = (unsigned*)alloc((size_t)N * 4);
    float*    dis        = (float*)alloc((size_t)N * 4);
    int*      col_src    = (int*)alloc((size_t)E * 4);
    unsigned short* xps  = (unsigned short*)alloc((size_t)N * DIM * 2);

    // pairs alias the xps region (E*8 = 12.8MB <= N*DIM*2 = 25.6MB): dead
    // before gemm_xw writes xps (stream-ordered), so no extra workspace.
    long long* pairs = (long long*)xps;
    if ((size_t)E * 8 > (size_t)N * DIM * 2 && off + (size_t)E * 8 <= ws_size)
        pairs = (long long*)alloc((size_t)E * 8);

    hipMemsetAsync(bcnt, 0, 4096, stream);
    hist_detect<<<512, 256, 0, stream>>>(ei, bcnt, E, shift);
    partition<<<(E + PCH - 1) / PCH, 256, 0, stream>>>(ei, bcnt, bcur0, pairs, E, B, shift);
    build_csr<<<B, 256, 0, stream>>>(pairs, bcnt, deg, row_start, dis, col_src, N, shift);
    gemm_xw<<<(N + 127) / 128, 256, 0, stream>>>(x, W, dis, xps, N);
    aggregate<<<(N + 3) / 4, 256, 0, stream>>>(xps, row_start, deg, dis, col_src, out, N);
}

// Round 10
// 243.832 us; speedup vs baseline: 1.2825x; 1.0308x over previous
//
#include <hip/hip_runtime.h>
#include <hip/hip_bf16.h>

#define DIM 128
#define PCH 4096   // edges per partition block (LDS-staged)

typedef __attribute__((ext_vector_type(8))) short bf16x8;
typedef __attribute__((ext_vector_type(4))) float f32x4;

__device__ __forceinline__ float bfu_lo(unsigned u) { return __uint_as_float(u << 16); }
__device__ __forceinline__ float bfu_hi(unsigned u) { return __uint_as_float(u & 0xffff0000u); }
__device__ __forceinline__ unsigned short f2bf(float f) {
    unsigned u = __float_as_uint(f);
    u += 0x7fffu + ((u >> 16) & 1u);   // round-to-nearest-even
    return (unsigned short)(u >> 16);
}

__device__ __forceinline__ int edge_at(const void* ei, int idx64, long long pos) {
    return idx64 ? (int)__builtin_nontemporal_load((const long long*)ei + pos)
                 : __builtin_nontemporal_load((const int*)ei + pos);
}

// Block-local edge-width sniff: returns 1 iff edge_index is int64 (odd 32-bit
// words -- high halves -- of the first min(E,4096) entries are all zero).
__device__ __forceinline__ int detect_idx64(const void* ei, int E, unsigned* s_or, int* s_flag) {
    const unsigned* ei_w = (const unsigned*)ei;
    int t = threadIdx.x;
    unsigned o = 0;
    int lim = (E < 4096) ? E : 4096;
    for (int k = t; k < lim; k += 256) o |= ei_w[2 * k + 1];
    s_or[t] = o;
    __syncthreads();
    for (int s = 128; s > 0; s >>= 1) {
        if (t < s) s_or[t] |= s_or[t + s];
        __syncthreads();
    }
    if (t == 0) *s_flag = (s_or[0] == 0u) ? 1 : 0;
    __syncthreads();
    return *s_flag;
}

// Bucket histogram of destinations (+fused width detect). Per-edge increments
// hit LDS; global atomics are only the per-block flush. bcnt pre-zeroed.
__global__ __launch_bounds__(256) void hist_detect(const void* ei, unsigned* bcnt,
                                                   int E, int shift) {
    __shared__ unsigned s_h[512];
    __shared__ unsigned s_or[256];
    __shared__ int s_flag;
    int t = threadIdx.x;
    for (int i = t; i < 512; i += 256) s_h[i] = 0u;
    int idx64 = detect_idx64(ei, E, s_or, &s_flag);
    long long stride = (long long)gridDim.x * 256;
    for (long long e = (long long)blockIdx.x * 256 + t; e < E; e += stride) {
        int d = edge_at(ei, idx64, (long long)E + e);
        atomicAdd(&s_h[d >> shift], 1u);
    }
    __syncthreads();
    for (int i = t; i < 512; i += 256)
        if (s_h[i]) atomicAdd(&bcnt[i], s_h[i]);
}

// LDS-staged partition of raw edges into destination buckets (shift=8,
// B<=512 buckets of 256 nodes -- R8 lesson: coarse buckets starve the build
// pass's grid; fine buckets keep B ~ 1.5x CUs). Flush position is computed
// directly from the staged d (R8's improvement -- no binary search).
__global__ __launch_bounds__(256) void partition(const void* ei, const unsigned* __restrict__ bcnt,
                                                 unsigned* bcur0, long long* pout,
                                                 int E, int B, int shift) {
    __shared__ unsigned s_hist[512], s_off[512], s_gbase[512], s_pref[512], s_bbase[512];
    __shared__ unsigned wsum[4];
    __shared__ unsigned s_or[256];
    __shared__ int s_flag;
    __shared__ long long s_p[PCH];
    int t = threadIdx.x;
    long long base = (long long)blockIdx.x * PCH;
    for (int i = t; i < 512; i += 256) { s_hist[i] = 0u; s_off[i] = 0u; }
    int idx64 = detect_idx64(ei, E, s_or, &s_flag);

    // local exclusive scan of global bucket counts -> s_bbase
    {
        unsigned v0 = bcnt[2 * t], v1 = bcnt[2 * t + 1];
        unsigned ps = v0 + v1;
        unsigned s = ps;
        int lane = t & 63;
#pragma unroll
        for (int off = 1; off < 64; off <<= 1) {
            unsigned u = __shfl_up(s, off, 64);
            if (lane >= off) s += u;
        }
        int w = t >> 6;
        if (lane == 63) wsum[w] = s;
        __syncthreads();
        unsigned woff = 0;
        for (int j = 0; j < w; j++) woff += wsum[j];
        unsigned excl = woff + s - ps;
        s_bbase[2 * t] = excl;
        s_bbase[2 * t + 1] = excl + v0;
    }
    __syncthreads();

    // load own edges into registers, LDS histogram
    int d_[PCH / 256], s_[PCH / 256];
#pragma unroll 4
    for (int j = 0; j < PCH / 256; j++) {
        long long e = base + j * 256 + t;
        if (e < E) {
            d_[j] = edge_at(ei, idx64, (long long)E + e);
            s_[j] = edge_at(ei, idx64, e);
            atomicAdd(&s_hist[d_[j] >> shift], 1u);
        } else d_[j] = -1;
    }
    __syncthreads();

    // exclusive scan of local 512 counts -> s_pref
    {
        unsigned v0 = s_hist[2 * t], v1 = s_hist[2 * t + 1];
        unsigned ps = v0 + v1;
        unsigned s = ps;
        int lane = t & 63;
#pragma unroll
        for (int off = 1; off < 64; off <<= 1) {
            unsigned u = __shfl_up(s, off, 64);
            if (lane >= off) s += u;
        }
        int w = t >> 6;
        if (lane == 63) wsum[w] = s;
        __syncthreads();
        unsigned woff = 0;
        for (int j = 0; j < w; j++) woff += wsum[j];
        unsigned excl = woff + s - ps;
        s_pref[2 * t] = excl;
        s_pref[2 * t + 1] = excl + v0;
    }
    __syncthreads();

    for (int i = t; i < B; i += 256)
        if (s_hist[i]) s_gbase[i] = s_bbase[i] + atomicAdd(&bcur0[i], s_hist[i]);
#pragma unroll 4
    for (int j = 0; j < PCH / 256; j++)
        if (d_[j] >= 0) {
            int b = d_[j] >> shift;
            unsigned p = s_pref[b] + atomicAdd(&s_off[b], 1u);
            s_p[p] = ((long long)s_[j] << 32) | (unsigned)d_[j];
        }
    __syncthreads();
    long long rem = (long long)E - base;
    unsigned tot = (rem < PCH) ? (unsigned)rem : (unsigned)PCH;
    for (unsigned i = t; i < tot; i += 256) {
        long long v = s_p[i];
        int b = ((int)v) >> shift;              // direct bucket recompute (no search)
        pout[s_gbase[b] + (i - s_pref[b])] = v;
    }
}

// One block per bucket (256 nodes). Recomputes bucket bases locally from
// bcnt. Degree histogram, prefix scan, dis, and CSR fill all via LDS
// counters -- zero global scattered atomics.
__global__ __launch_bounds__(256) void build_csr(const long long* __restrict__ pairs,
                                                 const unsigned* __restrict__ bcnt,
                                                 unsigned* deg, unsigned* row_start,
                                                 float* dis, int* col_src,
                                                 int N, int shift) {
    __shared__ unsigned cnt[512], cur[512], pref[512];
    __shared__ unsigned s_bb[513];
    __shared__ unsigned wsum[4];
    int b = blockIdx.x, t = threadIdx.x;
    int npb = 1 << shift;
    if (npb > 512) npb = 512;                   // defensive; caller guarantees <=512
    int nodeLo = b << shift;

    // local exclusive scan of global bucket counts -> bucket [lo,hi)
    {
        unsigned v0 = bcnt[2 * t], v1 = bcnt[2 * t + 1];
        unsigned ps = v0 + v1;
        unsigned s = ps;
        int lane = t & 63;
#pragma unroll
        for (int off = 1; off < 64; off <<= 1) {
            unsigned u = __shfl_up(s, off, 64);
            if (lane >= off) s += u;
        }
        int w = t >> 6;
        if (lane == 63) wsum[w] = s;
        __syncthreads();
        unsigned woff = 0;
        for (int j = 0; j < w; j++) woff += wsum[j];
        unsigned excl = woff + s - ps;
        s_bb[2 * t] = excl;
        s_bb[2 * t + 1] = excl + v0;
        if (t == 255) s_bb[512] = excl + ps;
    }
    __syncthreads();
    unsigned lo = s_bb[b], hi = s_bb[b + 1];

    for (int i = t; i < npb; i += 256) cnt[i] = 0u;
    __syncthreads();
    for (unsigned e = lo + t; e < hi; e += 256) {
        int d = (int)pairs[e];
        atomicAdd(&cnt[d - nodeLo], 1u);
    }
    __syncthreads();
    // exclusive scan of npb (<=512) counts, 2 per thread
    unsigned v0 = (2 * t < npb) ? cnt[2 * t] : 0u;
    unsigned v1 = (2 * t + 1 < npb) ? cnt[2 * t + 1] : 0u;
    unsigned ps = v0 + v1;
    unsigned s = ps;
    int lane = t & 63;
#pragma unroll
    for (int off = 1; off < 64; off <<= 1) {
        unsigned u = __shfl_up(s, off, 64);
        if (lane >= off) s += u;
    }
    int w = t >> 6;
    if (lane == 63) wsum[w] = s;
    __syncthreads();
    unsigned woff = 0;
    for (int j = 0; j < w; j++) woff += wsum[j];
    unsigned excl = woff + s - ps;
    if (2 * t < npb) pref[2 * t] = excl;
    if (2 * t + 1 < npb) pref[2 * t + 1] = excl + v0;
    __syncthreads();
    for (int i = t; i < npb; i += 256) {
        int node = nodeLo + i;
        unsigned rs = lo + pref[i];
        if (node < N) {
            unsigned c = cnt[i];
            deg[node] = c;
            row_start[node] = rs;
            dis[node] = rsqrtf((float)c + 1.0f);   // +1 self-loop
        }
        cur[i] = rs;
    }
    __syncthreads();
    for (unsigned e = lo + t; e < hi; e += 256) {
        long long v = pairs[e];
        int d = (int)v;
        int sv = (int)(v >> 32);
        unsigned pos = atomicAdd(&cur[d - nodeLo], 1u);
        col_src[pos] = sv;
    }
}

// xps = dis[row] * (x @ W), bf16 MFMA, fp32 x in / packed-bf16 out (pre-scaled).
// W transpose+bf16-convert fused into LDS (padded stride 136 shorts).
// Operand swap: mfma(Wfrag, Xfrag, acc) -> lane holds out[row=rowBase+l15][col=quad*4+reg]
__global__ __launch_bounds__(256) void gemm_xw(const float* __restrict__ x,
                                               const float* __restrict__ W,
                                               const float* __restrict__ dis,
                                               unsigned short* __restrict__ xps, int N) {
    __shared__ unsigned short wt[128 * 136];
    int tid = threadIdx.x;
    for (int idx = tid; idx < DIM * DIM; idx += 256) {
        int k = idx >> 7, n = idx & 127;        // idx = k*128+n -> coalesced W read
        wt[n * 136 + k] = f2bf(W[idx]);
    }
    __syncthreads();

    int wv = tid >> 6, lane = tid & 63;
    int l15 = lane & 15, quad = lane >> 4;
    int rowBase = blockIdx.x * 128 + wv * 32;

    f32x4 acc[2][8];
#pragma unroll
    for (int mt = 0; mt < 2; mt++)
#pragma unroll
        for (int nt = 0; nt < 8; nt++)
            acc[mt][nt] = (f32x4){0.f, 0.f, 0.f, 0.f};

#pragma unroll
    for (int k0 = 0; k0 < DIM; k0 += 32) {
        bf16x8 aa[2], bb[8];
#pragma unroll
        for (int mt = 0; mt < 2; mt++) {
            int r = rowBase + mt * 16 + l15;
            if (r > N - 1) r = N - 1;           // clamp; garbage rows never stored
            const float* xf = x + (size_t)r * DIM + k0 + quad * 8;
            float4 u0 = ((const float4*)xf)[0];
            float4 u1 = ((const float4*)xf)[1];
            bf16x8 a;
            a[0] = (short)f2bf(u0.x); a[1] = (short)f2bf(u0.y);
            a[2] = (short)f2bf(u0.z); a[3] = (short)f2bf(u0.w);
            a[4] = (short)f2bf(u1.x); a[5] = (short)f2bf(u1.y);
            a[6] = (short)f2bf(u1.z); a[7] = (short)f2bf(u1.w);
            aa[mt] = a;
        }
#pragma unroll
        for (int nt = 0; nt < 8; nt++)
            bb[nt] = *(const bf16x8*)(wt + (nt * 16 + l15) * 136 + k0 + quad * 8);
#pragma unroll
        for (int mt = 0; mt < 2; mt++)
#pragma unroll
            for (int nt = 0; nt < 8; nt++)
                acc[mt][nt] = __builtin_amdgcn_mfma_f32_16x16x32_bf16(bb[nt], aa[mt], acc[mt][nt], 0, 0, 0);
    }

#pragma unroll
    for (int mt = 0; mt < 2; mt++) {
        int r = rowBase + mt * 16 + l15;
        if (r < N) {
            float sc = dis[r];                  // pre-scale by source-side dis
#pragma unroll
            for (int nt = 0; nt < 8; nt++) {
                int c0 = nt * 16 + quad * 4;
                ushort4 o;
                o.x = f2bf(acc[mt][nt][0] * sc);
                o.y = f2bf(acc[mt][nt][1] * sc);
                o.z = f2bf(acc[mt][nt][2] * sc);
                o.w = f2bf(acc[mt][nt][3] * sc);
                *(ushort4*)(xps + (size_t)r * DIM + c0) = o;
            }
        }
    }
}

// One wave per node. 16 lanes per edge row (uint4 = 16B = 8 bf16 each), 4 edge
// slots per wave, inner loop unrolled x2 (8 slots / iter). Indices are
// prefetched 64-at-a-time (one coalesced load) and shfl-broadcast.
// EXACT R5 form: VGPR=28 -> 8 waves/SIMD; R7 (16-deep batch, VGPR 68) and
// R9 (depth-2 prefetch, VGPR 44) both REGRESSED -- TLP at max occupancy is
// what hides the random-gather latency, not per-wave ILP.
// Self-loop is virtual slot `cnt` (index wid). out[d] = dis[d] * sum(xps).
__global__ __launch_bounds__(256) void aggregate(const unsigned short* __restrict__ xps,
                                                 const unsigned* __restrict__ row_start,
                                                 const unsigned* __restrict__ deg,
                                                 const float* __restrict__ dis,
                                                 const int* __restrict__ col_src,
                                                 float* __restrict__ out, int N) {
    int wid = (int)((blockIdx.x * 256 + threadIdx.x) >> 6);
    if (wid >= N) return;
    int lane = threadIdx.x & 63;
    int grp = lane >> 4, lin = lane & 15;
    const uint4* xp4 = (const uint4*)xps;       // row = 16 x uint4

    float acc[8];
#pragma unroll
    for (int j = 0; j < 8; j++) acc[j] = 0.f;

    unsigned rs = row_start[wid];
    unsigned cnt = deg[wid];
    unsigned tot = cnt + 1;                      // + virtual self slot

    for (unsigned base = 0; base < tot; base += 64) {
        unsigned slot = base + (unsigned)lane;
        int idx = (slot < cnt) ? col_src[rs + slot] : wid;   // invalid/self -> wid (safe)
        unsigned rem = tot - base; if (rem > 64) rem = 64;
        for (unsigned q = 0; q * 8 < rem; q++) {
            unsigned sl0 = q * 8 + (unsigned)grp;
            unsigned sl1 = sl0 + 4;
            int s0 = __shfl(idx, (int)sl0, 64);
            int s1 = __shfl(idx, (int)sl1, 64);
            float m0 = (sl0 < rem) ? 1.f : 0.f;
            float m1 = (sl1 < rem) ? 1.f : 0.f;
            uint4 v0 = xp4[(size_t)s0 * 16 + lin];
            uint4 v1 = xp4[(size_t)s1 * 16 + lin];
            acc[0] = fmaf(bfu_lo(v0.x), m0, acc[0]);
            acc[1] = fmaf(bfu_hi(v0.x), m0, acc[1]);
            acc[2] = fmaf(bfu_lo(v0.y), m0, acc[2]);
            acc[3] = fmaf(bfu_hi(v0.y), m0, acc[3]);
            acc[4] = fmaf(bfu_lo(v0.z), m0, acc[4]);
            acc[5] = fmaf(bfu_hi(v0.z), m0, acc[5]);
            acc[6] = fmaf(bfu_lo(v0.w), m0, acc[6]);
            acc[7] = fmaf(bfu_hi(v0.w), m0, acc[7]);
            acc[0] = fmaf(bfu_lo(v1.x), m1, acc[0]);
            acc[1] = fmaf(bfu_hi(v1.x), m1, acc[1]);
            acc[2] = fmaf(bfu_lo(v1.y), m1, acc[2]);
            acc[3] = fmaf(bfu_hi(v1.y), m1, acc[3]);
            acc[4] = fmaf(bfu_lo(v1.z), m1, acc[4]);
            acc[5] = fmaf(bfu_hi(v1.z), m1, acc[5]);
            acc[6] = fmaf(bfu_lo(v1.w), m1, acc[6]);
            acc[7] = fmaf(bfu_hi(v1.w), m1, acc[7]);
        }
    }

    // reduce across the 4 groups (lanes differing in bits 4 and 5)
#pragma unroll
    for (int j = 0; j < 8; j++) {
        acc[j] += __shfl_xor(acc[j], 16, 64);
        acc[j] += __shfl_xor(acc[j], 32, 64);
    }

    float di = dis[wid];
    if (grp < 2) {                               // 32 lanes store the 512B row
        int jb = (grp & 1) * 4;
        float4 o;
        o.x = acc[jb + 0] * di;
        o.y = acc[jb + 1] * di;
        o.z = acc[jb + 2] * di;
        o.w = acc[jb + 3] * di;
        *(float4*)(out + (size_t)wid * DIM + lin * 8 + jb) = o;
    }
}

extern "C" void kernel_launch(void* const* d_in, const int* in_sizes, int n_in,
                              void* d_out, int out_size, void* d_ws, size_t ws_size,
                              hipStream_t stream) {
    const int N = in_sizes[0] / DIM;
    const int E = in_sizes[1] / 2;
    const float* x = (const float*)d_in[0];                     // fp32 [N][128]
    const void* ei = d_in[1];                                   // int32 or int64 [2][E]
    const float* W = (const float*)d_in[2];                     // fp32 [128][128]
    float* out = (float*)d_out;                                 // fp32 [N][128]

    // bucket geometry: 256 nodes per bucket (shift=8), B <= 512 buckets.
    // R8 lesson: coarse buckets (shift=11, B=49) starve build_csr's grid
    // (1.9% occupancy, 79us). B ~ 1.5x CU count is the sweet spot.
    int shift = 8;
    while ((((long long)N + (1LL << shift) - 1) >> shift) > 512 && shift < 9) shift++;
    int B = (int)(((long long)N + (1LL << shift) - 1) >> shift);

    char* wsp = (char*)d_ws;
    size_t off = 0;
    auto alloc = [&](size_t b) { void* p = wsp + off; off += (b + 255) & ~(size_t)255; return p; };
    unsigned* bcnt       = (unsigned*)alloc(4096);              // [0..511]=bcnt, [512..1023]=bcur0
    unsigned* bcur0      = bcnt + 512;
    unsigned* deg        = (unsigned*)alloc((size_t)N * 4);
    unsigned* row_start  = (unsigned*)alloc((size_t)N * 4);
    float*    dis        = (float*)alloc((size_t)N * 4);
    int*      col_src    = (int*)alloc((size_t)E * 4);
    unsigned short* xps  = (unsigned short*)alloc((size_t)N * DIM * 2);

    // pairs alias the xps region (E*8 = 12.8MB <= N*DIM*2 = 25.6MB): dead
    // before gemm_xw writes xps (stream-ordered), so no extra workspace.
    long long* pairs = (long long*)xps;
    if ((size_t)E * 8 > (size_t)N * DIM * 2 && off + (size_t)E * 8 <= ws_size)
        pairs = (long long*)alloc((size_t)E * 8);

    hipMemsetAsync(bcnt, 0, 4096, stream);
    hist_detect<<<512, 256, 0, stream>>>(ei, bcnt, E, shift);
    partition<<<(E + PCH - 1) / PCH, 256, 0, stream>>>(ei, bcnt, bcur0, pairs, E, B, shift);
    build_csr<<<B, 256, 0, stream>>>(pairs, bcnt, deg, row_start, dis, col_src, N, shift);
    gemm_xw<<<(N + 127) / 128, 256, 0, stream>>>(x, W, dis, xps, N);
    aggregate<<<(N + 3) / 4, 256, 0, stream>>>(xps, row_start, deg, dis, col_src, out, N);
}